// Round 1
// baseline (301.093 us; speedup 1.0000x reference)
//
#include <hip/hip_runtime.h>
#include <hip/hip_bf16.h>

// DecoderCell: attention (2-layer tanh MLP + softmax over L) + context + LSTM cell.
// Dims: L=512, B=256, Q=512, IN=512, H=1024, A=512, 4H=4096.
// Strategy:
//  - base[b][a] = h0 @ att1_w[:, :1024].T + att1_b  (l-invariant part, f32 tiled GEMM, split-K)
//  - big GEMM: hidden[l,b,a] = q[l,b,:] @ att1_w[:,1024:].T  (bf16 MFMA 16x16x32),
//    epilogue fuses +base, tanh, dot with att2_w -> att_raw (transposed [b][l]), no atomics.
//    A staged in LDS (XOR swizzle), B pre-packed in MFMA fragment order -> barrier-free K loop.
//  - softmax over l per b (faithful: max before mask), ctx = sum_l w*q.
//  - gates GEMM: [input|ctx|h_parent|h0] (bf16 frag-packed) x [W_ih|W_hh] (f32->bf16 on the fly),
//    split-K=4 partials, reduced in LSTM pointwise kernel.

typedef short bf16x8 __attribute__((ext_vector_type(8)));   // 8 bf16 = 4 VGPR
typedef float f32x4 __attribute__((ext_vector_type(4)));
typedef unsigned short u16x4 __attribute__((ext_vector_type(4)));

__device__ __forceinline__ unsigned short f2bf(float f) {   // RNE f32->bf16
  unsigned int u = __builtin_bit_cast(unsigned int, f);
  u += 0x7fffu + ((u >> 16) & 1u);
  return (unsigned short)(u >> 16);
}
__device__ __forceinline__ float fast_tanh(float x) {
  float e = __expf(2.0f * x);          // overflow -> inf -> tanh -> 1 (safe form)
  return 1.0f - 2.0f / (e + 1.0f);
}
__device__ __forceinline__ float fast_sig(float x) {
  return 1.0f / (1.0f + __expf(-x));
}
__device__ __forceinline__ f32x4 mfma16(bf16x8 a, bf16x8 b, f32x4 c) {
  return __builtin_amdgcn_mfma_f32_16x16x32_bf16(a, b, c, 0, 0, 0);
}

// ---------------- prep: att1_w query-part -> bf16 in MFMA B-fragment order ----------------
// frag id = ab*16 + ksf (ab: a-block of 16, ksf: k-step of 32). lane holds a=ab*16+(l&15),
// k=ksf*32+(l>>4)*8 .. +8. Stored so a wave's frag = 64 lanes x 16B consecutive (1KB).
__global__ void k_wqf(const float* __restrict__ a1w, unsigned short* __restrict__ wqf) {
  int g = blockIdx.x * 256 + threadIdx.x;      // 512 frags * 64 lanes = 32768
  int lane = g & 63, frag = g >> 6;
  int ab = frag >> 4, ksf = frag & 15;
  int a = ab * 16 + (lane & 15);
  int k = ksf * 32 + (lane >> 4) * 8;
  const float* src = a1w + (size_t)a * 1536 + 1024 + k;
  float4 v0 = *reinterpret_cast<const float4*>(src);
  float4 v1 = *reinterpret_cast<const float4*>(src + 4);
  unsigned short* dst = wqf + ((size_t)frag * 64 + lane) * 8;
  *(u16x4*)dst       = u16x4{ f2bf(v0.x), f2bf(v0.y), f2bf(v0.z), f2bf(v0.w) };
  *(u16x4*)(dst + 4) = u16x4{ f2bf(v1.x), f2bf(v1.y), f2bf(v1.z), f2bf(v1.w) };
}

// ---------------- base partials: h0 @ att1_w[:, :1024].T  (f32, tile 64x64, split-K 8) -----
__global__ void k_base1(const float* __restrict__ h0, const float* __restrict__ a1w,
                        float* __restrict__ part1) {
  int blk = blockIdx.x;                         // 256 = 8 ksp * 4 bt * 8 at
  int at = blk & 7, bt = (blk >> 3) & 3, ksp = blk >> 5;
  int a0 = at * 64, b0 = bt * 64, kbase = ksp * 128;
  __shared__ float sh[4096], sw[4096];          // 64x64 each, XOR-swizzled rows (256B)
  int t = threadIdx.x;
  int ta = t & 15, tb = t >> 4;                 // thread's a rows: ta+16j, b rows: tb+16i
  float acc[4][4] = {};
  for (int half = 0; half < 2; half++) {
    int k0 = kbase + half * 64;
    for (int i = 0; i < 4; i++) {
      int u = i * 256 + t;
      int row = u >> 4, c4 = (u & 15) << 2;
      float4 vh = *reinterpret_cast<const float4*>(h0 + (size_t)(b0 + row) * 1024 + k0 + c4);
      float4 vw = *reinterpret_cast<const float4*>(a1w + (size_t)(a0 + row) * 1536 + k0 + c4);
      int off = (row * 256 + c4 * 4) ^ ((row & 7) << 4);
      *(float4*)((char*)sh + off) = vh;
      *(float4*)((char*)sw + off) = vw;
    }
    __syncthreads();
    for (int k4 = 0; k4 < 16; k4++) {
      float4 hv[4], wv[4];
#pragma unroll
      for (int i = 0; i < 4; i++) {
        int rh = tb + 16 * i;
        hv[i] = *(const float4*)((char*)sh + ((rh * 256 + k4 * 16) ^ ((rh & 7) << 4)));
        int ra = ta + 16 * i;
        wv[i] = *(const float4*)((char*)sw + ((ra * 256 + k4 * 16) ^ ((ra & 7) << 4)));
      }
#pragma unroll
      for (int i = 0; i < 4; i++)
#pragma unroll
        for (int j = 0; j < 4; j++)
          acc[i][j] += hv[i].x * wv[j].x + hv[i].y * wv[j].y +
                       hv[i].z * wv[j].z + hv[i].w * wv[j].w;
    }
    __syncthreads();
  }
  float* dst = part1 + (size_t)ksp * 131072;
#pragma unroll
  for (int i = 0; i < 4; i++)
#pragma unroll
    for (int j = 0; j < 4; j++)
      dst[(size_t)(b0 + tb + 16 * i) * 512 + a0 + ta + 16 * j] = acc[i][j];
}

__global__ void k_base2(const float* __restrict__ part1, const float* __restrict__ a1b,
                        float* __restrict__ base) {
  int idx = blockIdx.x * 256 + threadIdx.x;     // 131072
  float s = a1b[idx & 511];
  for (int ks = 0; ks < 8; ks++) s += part1[(size_t)ks * 131072 + idx];
  base[idx] = s;
}

// ---------------- big GEMM + fused tanh/att2 reduction ----------------
// Block: 64 rows (m = l*256+b), 4 waves over N (cols), 2 chunks of 256.
// A: f32->bf16 staged once to LDS [64][512] (XOR swizzle). B: direct frag loads from wqf (L2).
// Barrier-free K loop; epilogue: val=acc+base[b][a]; rowsum += tanh(val)*att2_w[a].
__global__ __launch_bounds__(256, 2) void k_attgemm(
    const float* __restrict__ qd, const unsigned short* __restrict__ wqf,
    const float* __restrict__ base, const float* __restrict__ w2,
    float* __restrict__ araw) {
  extern __shared__ char smem[];                 // 65536: sA [64][512] bf16 swizzled
  int t = threadIdx.x;
  int m0 = blockIdx.x * 64;
  for (int i = 0; i < 32; i++) {                 // stage A: 128KB f32 -> 64KB bf16
    int u = i * 256 + t;
    int row = u >> 7, c4 = (u & 127) << 2;
    float4 v = *reinterpret_cast<const float4*>(qd + (size_t)(m0 + row) * 512 + c4);
    int off = (row * 1024 + c4 * 2) ^ ((row & 7) << 4);
    *(u16x4*)(smem + off) = u16x4{ f2bf(v.x), f2bf(v.y), f2bf(v.z), f2bf(v.w) };
  }
  __syncthreads();
  int lane = t & 63, lr = lane & 15, lh = lane >> 4;
  int w = t >> 6;
  int b0 = m0 & 255;                             // m0 multiple of 64 -> b = b0+row, no wrap
  float rs[4][4] = {};                           // [mi][reg] row-sums
  for (int chunk = 0; chunk < 2; chunk++) {
    f32x4 acc[4][4] = {};                        // [mi][ni]
    int colbase = chunk * 256 + w * 64;
#pragma unroll 4
    for (int ks = 0; ks < 16; ks++) {
      bf16x8 aF[4], bF[4];
#pragma unroll
      for (int mi = 0; mi < 4; mi++) {
        int row = mi * 16 + lr;
        int off = (row * 1024 + (ks * 32 + lh * 8) * 2) ^ ((row & 7) << 4);
        aF[mi] = *(const bf16x8*)(smem + off);
      }
#pragma unroll
      for (int ni = 0; ni < 4; ni++) {
        int ab = (colbase >> 4) + ni;
        bF[ni] = *(const bf16x8*)(wqf + ((size_t)(ab * 16 + ks) * 64 + lane) * 8);
      }
#pragma unroll
      for (int mi = 0; mi < 4; mi++)
#pragma unroll
        for (int ni = 0; ni < 4; ni++)
          acc[mi][ni] = mfma16(aF[mi], bF[ni], acc[mi][ni]);
    }
#pragma unroll
    for (int ni = 0; ni < 4; ni++) {             // fused epilogue for this chunk
      int a = colbase + ni * 16 + lr;
      float w2v = w2[a];
#pragma unroll
      for (int mi = 0; mi < 4; mi++)
#pragma unroll
        for (int r = 0; r < 4; r++) {
          int row = mi * 16 + lh * 4 + r;
          float val = acc[mi][ni][r] + base[(size_t)(b0 + row) * 512 + a];
          rs[mi][r] += fast_tanh(val) * w2v;
        }
    }
  }
#pragma unroll
  for (int mi = 0; mi < 4; mi++)                 // reduce over the 16 cols held across lr
#pragma unroll
    for (int r = 0; r < 4; r++) {
      float v = rs[mi][r];
      v += __shfl_xor(v, 1); v += __shfl_xor(v, 2);
      v += __shfl_xor(v, 4); v += __shfl_xor(v, 8);
      rs[mi][r] = v;
    }
  __syncthreads();                               // all A-reads done -> reuse smem for sRed
  float* sRed = (float*)smem;                    // [4 waves][64 rows]
  if (lr == 0)
#pragma unroll
    for (int mi = 0; mi < 4; mi++)
#pragma unroll
      for (int r = 0; r < 4; r++)
        sRed[w * 64 + mi * 16 + lh * 4 + r] = rs[mi][r];
  __syncthreads();
  if (t < 64) {
    float v = sRed[t] + sRed[64 + t] + sRed[128 + t] + sRed[192 + t];
    int m = m0 + t;
    araw[(size_t)(m & 255) * 512 + (m >> 8) ] = v;   // transposed [b][l]
  }
}

// ---------------- softmax over l per b (faithful: max before mask) ----------------
__global__ void k_softmax(const float* __restrict__ araw, const float* __restrict__ mask,
                          float* __restrict__ wt) {
  int b = blockIdx.x, t = threadIdx.x;
  float x0 = araw[b * 512 + t];
  float x1 = araw[b * 512 + t + 256];
  float mx = fmaxf(x0, x1);
#pragma unroll
  for (int off = 1; off < 64; off <<= 1) mx = fmaxf(mx, __shfl_xor(mx, off));
  __shared__ float red[8];
  int wv = t >> 6, ln = t & 63;
  if (ln == 0) red[wv] = mx;
  __syncthreads();
  mx = fmaxf(fmaxf(red[0], red[1]), fmaxf(red[2], red[3]));
  float e0 = __expf(x0 - mx) * mask[(size_t)t * 256 + b];
  float e1 = __expf(x1 - mx) * mask[(size_t)(t + 256) * 256 + b];
  float s = e0 + e1;
#pragma unroll
  for (int off = 1; off < 64; off <<= 1) s += __shfl_xor(s, off);
  if (ln == 0) red[4 + wv] = s;
  __syncthreads();
  s = red[4] + red[5] + red[6] + red[7];
  float inv = 1.0f / s;
  wt[b * 512 + t] = e0 * inv;
  wt[b * 512 + t + 256] = e1 * inv;
}

// ---------------- ctx[b][q] = sum_l w[b][l] * qd[l][b][q]  (f32, coalesced) ----------------
__global__ void k_ctx(const float* __restrict__ qd, const float* __restrict__ wt,
                      float* __restrict__ out) {
  __shared__ float sw[512];
  int b = blockIdx.x >> 1, qh = blockIdx.x & 1;
  int t = threadIdx.x;
  sw[t] = wt[b * 512 + t];
  sw[t + 256] = wt[b * 512 + t + 256];
  __syncthreads();
  int q = qh * 256 + t;
  const float* src = qd + (size_t)b * 512 + q;
  float acc = 0.0f;
#pragma unroll 16
  for (int l = 0; l < 512; l++)
    acc += src[(size_t)l * 131072] * sw[l];
  out[b * 512 + q] = acc;                        // ctx at d_out offset 0
}

// ---------------- build x = [input|ctx|h_parent|h0] in bf16 MFMA A-fragment order --------
// frag = mb*96 + kstep (mb: b-block of 16, kstep: k-step of 32 over K=3072)
__global__ void k_xf(const float* __restrict__ inp, const float* __restrict__ ctx,
                     const float* __restrict__ hist, const int* __restrict__ pidx,
                     const float* __restrict__ h0, unsigned short* __restrict__ xf) {
  int g = blockIdx.x * 256 + threadIdx.x;        // 1536 frags * 64 lanes = 98304
  int lane = g & 63, frag = g >> 6;
  int mb = frag / 96, kstep = frag % 96;
  int b = mb * 16 + (lane & 15);
  int k = kstep * 32 + (lane >> 4) * 8;
  const float* src;
  if (k < 512)       src = inp  + (size_t)b * 512 + k;
  else if (k < 1024) src = ctx  + (size_t)b * 512 + (k - 512);
  else if (k < 2048) src = hist + ((size_t)pidx[b] * 256 + b) * 1024 + (k - 1024);
  else               src = h0   + (size_t)b * 1024 + (k - 2048);
  float4 v0 = *reinterpret_cast<const float4*>(src);
  float4 v1 = *reinterpret_cast<const float4*>(src + 4);
  unsigned short* dst = xf + ((size_t)frag * 64 + lane) * 8;
  *(u16x4*)dst       = u16x4{ f2bf(v0.x), f2bf(v0.y), f2bf(v0.z), f2bf(v0.w) };
  *(u16x4*)(dst + 4) = u16x4{ f2bf(v1.x), f2bf(v1.y), f2bf(v1.z), f2bf(v1.w) };
}

// ---------------- gates GEMM: (256 x 3072) x (4096 x 3072)^T, split-K 4 -------------------
// No LDS, no barriers: A-frags from packed xf (L2-hot), B-frags direct f32 loads + cvt.
__global__ __launch_bounds__(512, 2) void k_gates(
    const unsigned short* __restrict__ xf, const float* __restrict__ Wih,
    const float* __restrict__ Whh, float* __restrict__ part) {
  int blk = blockIdx.x;                          // 128 = 32 ntiles * 4 ksplit
  int nt = blk & 31, ksp = blk >> 5;
  int n0 = nt * 128;
  int kbeg = ksp * 768;
  int t = threadIdx.x;
  int lane = t & 63, lr = lane & 15, lh = lane >> 4;
  int w = t >> 6, wm = w >> 1, wn = w & 1;       // wave tile 64(b) x 64(j)
  f32x4 acc[4][4] = {};
#pragma unroll 2
  for (int ks = 0; ks < 24; ks++) {
    int k0 = kbeg + ks * 32;
    bf16x8 aF[4], bF[4];
    int kstep = k0 >> 5;
#pragma unroll
    for (int mi = 0; mi < 4; mi++) {
      int mb = wm * 4 + mi;
      aF[mi] = *(const bf16x8*)(xf + ((size_t)(mb * 96 + kstep) * 64 + lane) * 8);
    }
    const float* Wp; int ldw, kk;
    if (k0 < 2048) { Wp = Wih; ldw = 2048; kk = k0; }
    else           { Wp = Whh; ldw = 1024; kk = k0 - 2048; }
#pragma unroll
    for (int ni = 0; ni < 4; ni++) {
      int j = n0 + wn * 64 + ni * 16 + lr;
      const float* src = Wp + (size_t)j * ldw + kk + lh * 8;
      float4 v0 = *reinterpret_cast<const float4*>(src);
      float4 v1 = *reinterpret_cast<const float4*>(src + 4);
      bf16x8 bv;
      bv[0] = (short)f2bf(v0.x); bv[1] = (short)f2bf(v0.y);
      bv[2] = (short)f2bf(v0.z); bv[3] = (short)f2bf(v0.w);
      bv[4] = (short)f2bf(v1.x); bv[5] = (short)f2bf(v1.y);
      bv[6] = (short)f2bf(v1.z); bv[7] = (short)f2bf(v1.w);
      bF[ni] = bv;
    }
#pragma unroll
    for (int mi = 0; mi < 4; mi++)
#pragma unroll
      for (int ni = 0; ni < 4; ni++)
        acc[mi][ni] = mfma16(aF[mi], bF[ni], acc[mi][ni]);
  }
  float* dst = part + (size_t)ksp * (256 * 4096);
#pragma unroll
  for (int mi = 0; mi < 4; mi++)
#pragma unroll
    for (int ni = 0; ni < 4; ni++)
#pragma unroll
      for (int r = 0; r < 4; r++) {
        int b = wm * 64 + mi * 16 + lh * 4 + r;
        int j = n0 + wn * 64 + ni * 16 + lr;
        dst[(size_t)b * 4096 + j] = acc[mi][ni][r];
      }
}

// ---------------- LSTM pointwise: reduce split-K partials + gates + outputs ---------------
__global__ void k_lstm(const float* __restrict__ part, const float* __restrict__ bih,
                       const float* __restrict__ bhh, const float* __restrict__ c0,
                       float* __restrict__ out) {
  int idx = blockIdx.x * 256 + threadIdx.x;      // 262144
  int h = idx & 1023;
  int b = idx >> 10;
  const float* p = part + (size_t)b * 4096;
  float gi = bih[h] + bhh[h];
  float gf = bih[1024 + h] + bhh[1024 + h];
  float gg = bih[2048 + h] + bhh[2048 + h];
  float go = bih[3072 + h] + bhh[3072 + h];
#pragma unroll
  for (int ks = 0; ks < 4; ks++) {
    const float* q = p + (size_t)ks * 1048576;
    gi += q[h]; gf += q[1024 + h]; gg += q[2048 + h]; go += q[3072 + h];
  }
  float c = fast_sig(gf) * c0[idx] + fast_sig(gi) * fast_tanh(gg);
  float hv = fast_sig(go) * fast_tanh(c);
  out[131072 + idx] = hv;                        // h1
  out[393216 + idx] = c;                         // c1
}

extern "C" void kernel_launch(void* const* d_in, const int* in_sizes, int n_in,
                              void* d_out, int out_size, void* d_ws, size_t ws_size,
                              hipStream_t stream) {
  const float* qd    = (const float*)d_in[0];
  const float* qmask = (const float*)d_in[1];
  const float* inp   = (const float*)d_in[2];
  const int*   pidx  = (const int*)d_in[3];
  const float* hist  = (const float*)d_in[4];
  const float* h0    = (const float*)d_in[5];
  const float* c0    = (const float*)d_in[6];
  const float* Wih   = (const float*)d_in[7];
  const float* Whh   = (const float*)d_in[8];
  const float* bih   = (const float*)d_in[9];
  const float* bhh   = (const float*)d_in[10];
  const float* a1w   = (const float*)d_in[11];
  const float* a1b   = (const float*)d_in[12];
  const float* a2w   = (const float*)d_in[13];
  float* outF = (float*)d_out;

  char* ws = (char*)d_ws;                         // ~23.5 MB used
  unsigned short* wqf  = (unsigned short*)(ws);                 // 512 KB
  float*          base = (float*)(ws + 524288);                  // 512 KB
  float*          araw = (float*)(ws + 1048576);                 // 512 KB
  float*          wt   = (float*)(ws + 1572864);                 // 512 KB
  unsigned short* xf   = (unsigned short*)(ws + 2097152);        // 1.5 MB
  float*          p1   = (float*)(ws + 3670016);                 // 4 MB
  float*          pg   = (float*)(ws + 7864320);                 // 16 MB

  (void)hipFuncSetAttribute((const void*)k_attgemm,
                            hipFuncAttributeMaxDynamicSharedMemorySize, 65536);

  k_wqf    <<<128,  256, 0, stream>>>(a1w, wqf);
  k_base1  <<<256,  256, 0, stream>>>(h0, a1w, p1);
  k_base2  <<<512,  256, 0, stream>>>(p1, a1b, base);
  k_attgemm<<<2048, 256, 65536, stream>>>(qd, wqf, base, a2w, araw);
  k_softmax<<<256,  256, 0, stream>>>(araw, qmask, wt);
  k_ctx    <<<512,  256, 0, stream>>>(qd, wt, outF);
  k_xf     <<<384,  256, 0, stream>>>(inp, outF, hist, pidx, h0, xf);
  k_gates  <<<128,  512, 0, stream>>>(xf, Wih, Whh, pg);
  k_lstm   <<<1024, 256, 0, stream>>>(pg, bih, bhh, c0, outF);
}

// Round 2
// 290.982 us; speedup vs baseline: 1.0347x; 1.0347x over previous
//
#include <hip/hip_runtime.h>
#include <hip/hip_bf16.h>

// DecoderCell: attention (2-layer tanh MLP + softmax over L) + context + LSTM cell.
// Dims: L=512, B=256, Q=512, IN=512, H=1024, A=512, 4H=4096.
// R2 changes vs R1:
//  - attgemm also writes bf16-swizzled qd copy (qbf) -> ctx reads bf16 (halves ctx traffic)
//  - softmax fused into ctx (per-b), wt buffer gone
//  - wqf + base1 merged into one dispatch (k_prep)
//  - gates re-tiled to 256 blocks (full CU coverage)

typedef short bf16x8 __attribute__((ext_vector_type(8)));   // 8 bf16 = 4 VGPR
typedef float f32x4 __attribute__((ext_vector_type(4)));
typedef unsigned short u16x4 __attribute__((ext_vector_type(4)));

__device__ __forceinline__ unsigned short f2bf(float f) {   // RNE f32->bf16
  unsigned int u = __builtin_bit_cast(unsigned int, f);
  u += 0x7fffu + ((u >> 16) & 1u);
  return (unsigned short)(u >> 16);
}
__device__ __forceinline__ float bf2f(unsigned short u) {
  unsigned int x = (unsigned int)u << 16;
  return __builtin_bit_cast(float, x);
}
__device__ __forceinline__ float fast_tanh(float x) {
  float e = __expf(2.0f * x);          // overflow -> inf -> tanh -> 1 (safe form)
  return 1.0f - 2.0f / (e + 1.0f);
}
__device__ __forceinline__ float fast_sig(float x) {
  return 1.0f / (1.0f + __expf(-x));
}
__device__ __forceinline__ f32x4 mfma16(bf16x8 a, bf16x8 b, f32x4 c) {
  return __builtin_amdgcn_mfma_f32_16x16x32_bf16(a, b, c, 0, 0, 0);
}

// ---------------- prep: (blocks 0..127) att1_w query-part -> bf16 B-frags
//                  (blocks 128..383) base partials h0 @ att1_w[:, :1024].T ----------------
__global__ void k_prep(const float* __restrict__ a1w, const float* __restrict__ h0,
                       unsigned short* __restrict__ wqf, float* __restrict__ part1) {
  __shared__ float sh[4096], swt[4096];
  int bx = blockIdx.x;
  if (bx < 128) {                               // ---- wqf role ----
    int g = bx * 256 + threadIdx.x;             // 512 frags * 64 lanes = 32768
    int lane = g & 63, frag = g >> 6;
    int ab = frag >> 4, ksf = frag & 15;
    int a = ab * 16 + (lane & 15);
    int k = ksf * 32 + (lane >> 4) * 8;
    const float* src = a1w + (size_t)a * 1536 + 1024 + k;
    float4 v0 = *reinterpret_cast<const float4*>(src);
    float4 v1 = *reinterpret_cast<const float4*>(src + 4);
    unsigned short* dst = wqf + ((size_t)frag * 64 + lane) * 8;
    *(u16x4*)dst       = u16x4{ f2bf(v0.x), f2bf(v0.y), f2bf(v0.z), f2bf(v0.w) };
    *(u16x4*)(dst + 4) = u16x4{ f2bf(v1.x), f2bf(v1.y), f2bf(v1.z), f2bf(v1.w) };
    return;
  }
  // ---- base1 role: tile 64x64, split-K 8 ----
  int blk = bx - 128;                           // 256 = 8 ksp * 4 bt * 8 at
  int at = blk & 7, bt = (blk >> 3) & 3, ksp = blk >> 5;
  int a0 = at * 64, b0 = bt * 64, kbase = ksp * 128;
  int t = threadIdx.x;
  int ta = t & 15, tb = t >> 4;
  float acc[4][4] = {};
  for (int half = 0; half < 2; half++) {
    int k0 = kbase + half * 64;
    for (int i = 0; i < 4; i++) {
      int u = i * 256 + t;
      int row = u >> 4, c4 = (u & 15) << 2;
      float4 vh = *reinterpret_cast<const float4*>(h0 + (size_t)(b0 + row) * 1024 + k0 + c4);
      float4 vw = *reinterpret_cast<const float4*>(a1w + (size_t)(a0 + row) * 1536 + k0 + c4);
      int off = (row * 256 + c4 * 4) ^ ((row & 7) << 4);
      *(float4*)((char*)sh + off) = vh;
      *(float4*)((char*)swt + off) = vw;
    }
    __syncthreads();
    for (int k4 = 0; k4 < 16; k4++) {
      float4 hv[4], wv[4];
#pragma unroll
      for (int i = 0; i < 4; i++) {
        int rh = tb + 16 * i;
        hv[i] = *(const float4*)((char*)sh + ((rh * 256 + k4 * 16) ^ ((rh & 7) << 4)));
        int ra = ta + 16 * i;
        wv[i] = *(const float4*)((char*)swt + ((ra * 256 + k4 * 16) ^ ((ra & 7) << 4)));
      }
#pragma unroll
      for (int i = 0; i < 4; i++)
#pragma unroll
        for (int j = 0; j < 4; j++)
          acc[i][j] += hv[i].x * wv[j].x + hv[i].y * wv[j].y +
                       hv[i].z * wv[j].z + hv[i].w * wv[j].w;
    }
    __syncthreads();
  }
  float* dst = part1 + (size_t)ksp * 131072;
#pragma unroll
  for (int i = 0; i < 4; i++)
#pragma unroll
    for (int j = 0; j < 4; j++)
      dst[(size_t)(b0 + tb + 16 * i) * 512 + a0 + ta + 16 * j] = acc[i][j];
}

__global__ void k_base2(const float* __restrict__ part1, const float* __restrict__ a1b,
                        float* __restrict__ base) {
  int idx = blockIdx.x * 256 + threadIdx.x;     // 131072
  float s = a1b[idx & 511];
  for (int ks = 0; ks < 8; ks++) s += part1[(size_t)ks * 131072 + idx];
  base[idx] = s;
}

// ---------------- big GEMM + fused tanh/att2 reduction + qbf side-store ----------------
// Block: 64 rows (m = l*256+b), 4 waves over N (cols), 2 chunks of 256.
// A: f32->bf16 staged to LDS [64][512] (XOR swizzle) AND stored to qbf (same layout, global).
// B: direct frag loads from wqf (L2). Barrier-free K loop.
__global__ __launch_bounds__(256, 2) void k_attgemm(
    const float* __restrict__ qd, const unsigned short* __restrict__ wqf,
    const float* __restrict__ base, const float* __restrict__ w2,
    float* __restrict__ araw, unsigned short* __restrict__ qbf) {
  extern __shared__ char smem[];                 // 65536: sA [64][512] bf16 swizzled
  int t = threadIdx.x;
  int m0 = blockIdx.x * 64;
  for (int i = 0; i < 32; i++) {                 // stage A: 128KB f32 -> 64KB bf16
    int u = i * 256 + t;
    int row = u >> 7, c4 = (u & 127) << 2;
    float4 v = *reinterpret_cast<const float4*>(qd + (size_t)(m0 + row) * 512 + c4);
    int off = (row * 1024 + c4 * 2) ^ ((row & 7) << 4);
    u16x4 bv = u16x4{ f2bf(v.x), f2bf(v.y), f2bf(v.z), f2bf(v.w) };
    *(u16x4*)(smem + off) = bv;
    *(u16x4*)((char*)qbf + (size_t)m0 * 1024 + off) = bv;   // bf16 copy for k_ctx
  }
  __syncthreads();
  int lane = t & 63, lr = lane & 15, lh = lane >> 4;
  int w = t >> 6;
  int b0 = m0 & 255;                             // m0 multiple of 64 -> b = b0+row, no wrap
  float rs[4][4] = {};                           // [mi][reg] row-sums
  for (int chunk = 0; chunk < 2; chunk++) {
    f32x4 acc[4][4] = {};                        // [mi][ni]
    int colbase = chunk * 256 + w * 64;
#pragma unroll 4
    for (int ks = 0; ks < 16; ks++) {
      bf16x8 aF[4], bF[4];
#pragma unroll
      for (int mi = 0; mi < 4; mi++) {
        int row = mi * 16 + lr;
        int off = (row * 1024 + (ks * 32 + lh * 8) * 2) ^ ((row & 7) << 4);
        aF[mi] = *(const bf16x8*)(smem + off);
      }
#pragma unroll
      for (int ni = 0; ni < 4; ni++) {
        int ab = (colbase >> 4) + ni;
        bF[ni] = *(const bf16x8*)(wqf + ((size_t)(ab * 16 + ks) * 64 + lane) * 8);
      }
#pragma unroll
      for (int mi = 0; mi < 4; mi++)
#pragma unroll
        for (int ni = 0; ni < 4; ni++)
          acc[mi][ni] = mfma16(aF[mi], bF[ni], acc[mi][ni]);
    }
#pragma unroll
    for (int ni = 0; ni < 4; ni++) {             // fused epilogue for this chunk
      int a = colbase + ni * 16 + lr;
      float w2v = w2[a];
#pragma unroll
      for (int mi = 0; mi < 4; mi++)
#pragma unroll
        for (int r = 0; r < 4; r++) {
          int row = mi * 16 + lh * 4 + r;
          float val = acc[mi][ni][r] + base[(size_t)(b0 + row) * 512 + a];
          rs[mi][r] += fast_tanh(val) * w2v;
        }
    }
  }
#pragma unroll
  for (int mi = 0; mi < 4; mi++)                 // reduce over the 16 cols held across lr
#pragma unroll
    for (int r = 0; r < 4; r++) {
      float v = rs[mi][r];
      v += __shfl_xor(v, 1); v += __shfl_xor(v, 2);
      v += __shfl_xor(v, 4); v += __shfl_xor(v, 8);
      rs[mi][r] = v;
    }
  __syncthreads();                               // all A-reads done -> reuse smem for sRed
  float* sRed = (float*)smem;                    // [4 waves][64 rows]
  if (lr == 0)
#pragma unroll
    for (int mi = 0; mi < 4; mi++)
#pragma unroll
      for (int r = 0; r < 4; r++)
        sRed[w * 64 + mi * 16 + lh * 4 + r] = rs[mi][r];
  __syncthreads();
  if (t < 64) {
    float v = sRed[t] + sRed[64 + t] + sRed[128 + t] + sRed[192 + t];
    int m = m0 + t;
    araw[(size_t)(m & 255) * 512 + (m >> 8)] = v;   // transposed [b][l]
  }
}

// ---------------- fused softmax + ctx: one block per b ----------------
// softmax over l (faithful: max before mask), then ctx[b][q] = sum_l w[l]*qbf[l,b,q].
__global__ __launch_bounds__(256, 4) void k_ctx(
    const unsigned short* __restrict__ qbf, const float* __restrict__ araw,
    const float* __restrict__ mask, float* __restrict__ out) {
  __shared__ float sw[512];
  __shared__ float red[8];
  __shared__ float sRed[4][512];
  int b = blockIdx.x, t = threadIdx.x;
  float x0 = araw[b * 512 + t];
  float x1 = araw[b * 512 + t + 256];
  float mx = fmaxf(x0, x1);
#pragma unroll
  for (int off = 1; off < 64; off <<= 1) mx = fmaxf(mx, __shfl_xor(mx, off));
  int wv = t >> 6, ln = t & 63;
  if (ln == 0) red[wv] = mx;
  __syncthreads();
  mx = fmaxf(fmaxf(red[0], red[1]), fmaxf(red[2], red[3]));
  float e0 = __expf(x0 - mx) * mask[(size_t)t * 256 + b];
  float e1 = __expf(x1 - mx) * mask[(size_t)(t + 256) * 256 + b];
  float s = e0 + e1;
#pragma unroll
  for (int off = 1; off < 64; off <<= 1) s += __shfl_xor(s, off);
  if (ln == 0) red[4 + wv] = s;
  __syncthreads();
  s = red[4] + red[5] + red[6] + red[7];
  float inv = 1.0f / s;
  sw[t] = e0 * inv;
  sw[t + 256] = e1 * inv;
  __syncthreads();
  // weighted sum: wave ls handles 128 l's; thread owns 8 q's (16B chunk qc)
  int qc = t & 63, ls = t >> 6;
  const char* basep = (const char*)qbf + (size_t)b * 1024 + ((size_t)(qc ^ (b & 7)) << 4);
  float acc[8] = {};
#pragma unroll 8
  for (int i = 0; i < 128; i++) {
    int l = ls * 128 + i;
    uint4 v = *(const uint4*)(basep + (size_t)l * 262144);
    float wl = sw[l];
    acc[0] += wl * bf2f((unsigned short)(v.x & 0xffff));
    acc[1] += wl * bf2f((unsigned short)(v.x >> 16));
    acc[2] += wl * bf2f((unsigned short)(v.y & 0xffff));
    acc[3] += wl * bf2f((unsigned short)(v.y >> 16));
    acc[4] += wl * bf2f((unsigned short)(v.z & 0xffff));
    acc[5] += wl * bf2f((unsigned short)(v.z >> 16));
    acc[6] += wl * bf2f((unsigned short)(v.w & 0xffff));
    acc[7] += wl * bf2f((unsigned short)(v.w >> 16));
  }
#pragma unroll
  for (int j = 0; j < 8; j++) sRed[ls][qc * 8 + j] = acc[j];
  __syncthreads();
  for (int q = t; q < 512; q += 256)
    out[b * 512 + q] = sRed[0][q] + sRed[1][q] + sRed[2][q] + sRed[3][q];
}

// ---------------- build x = [input|ctx|h_parent|h0] in bf16 MFMA A-fragment order --------
__global__ void k_xf(const float* __restrict__ inp, const float* __restrict__ ctx,
                     const float* __restrict__ hist, const int* __restrict__ pidx,
                     const float* __restrict__ h0, unsigned short* __restrict__ xf) {
  int g = blockIdx.x * 256 + threadIdx.x;        // 1536 frags * 64 lanes = 98304
  int lane = g & 63, frag = g >> 6;
  int mb = frag / 96, kstep = frag % 96;
  int b = mb * 16 + (lane & 15);
  int k = kstep * 32 + (lane >> 4) * 8;
  const float* src;
  if (k < 512)       src = inp  + (size_t)b * 512 + k;
  else if (k < 1024) src = ctx  + (size_t)b * 512 + (k - 512);
  else if (k < 2048) src = hist + ((size_t)pidx[b] * 256 + b) * 1024 + (k - 1024);
  else               src = h0   + (size_t)b * 1024 + (k - 2048);
  float4 v0 = *reinterpret_cast<const float4*>(src);
  float4 v1 = *reinterpret_cast<const float4*>(src + 4);
  unsigned short* dst = xf + ((size_t)frag * 64 + lane) * 8;
  *(u16x4*)dst       = u16x4{ f2bf(v0.x), f2bf(v0.y), f2bf(v0.z), f2bf(v0.w) };
  *(u16x4*)(dst + 4) = u16x4{ f2bf(v1.x), f2bf(v1.y), f2bf(v1.z), f2bf(v1.w) };
}

// ---------------- gates GEMM: (256 x 3072) x (4096 x 3072)^T, 64 nt x 4 ksp = 256 blocks --
// No LDS, no barriers: A-frags from packed xf (L2-hot), B-frags direct f32 loads + cvt.
__global__ __launch_bounds__(256, 2) void k_gates(
    const unsigned short* __restrict__ xf, const float* __restrict__ Wih,
    const float* __restrict__ Whh, float* __restrict__ part) {
  int blk = blockIdx.x;                          // 256 = 64 nt * 4 ksp
  int nt = blk & 63, ksp = blk >> 6;
  int n0 = nt * 64, kbeg = ksp * 768;
  int t = threadIdx.x;
  int lane = t & 63, lr = lane & 15, lh = lane >> 4;
  int w = t >> 6;                                // wave covers b-range w*64
  f32x4 acc[4][4] = {};
#pragma unroll 2
  for (int ks = 0; ks < 24; ks++) {
    int k0 = kbeg + ks * 32;
    int kstep = k0 >> 5;
    bf16x8 aF[4], bF[4];
#pragma unroll
    for (int mi = 0; mi < 4; mi++) {
      int mb = w * 4 + mi;
      aF[mi] = *(const bf16x8*)(xf + ((size_t)(mb * 96 + kstep) * 64 + lane) * 8);
    }
    const float* Wp; int ldw, kk;
    if (k0 < 2048) { Wp = Wih; ldw = 2048; kk = k0; }
    else           { Wp = Whh; ldw = 1024; kk = k0 - 2048; }
#pragma unroll
    for (int ni = 0; ni < 4; ni++) {
      int j = n0 + ni * 16 + lr;
      const float* src = Wp + (size_t)j * ldw + kk + lh * 8;
      float4 v0 = *reinterpret_cast<const float4*>(src);
      float4 v1 = *reinterpret_cast<const float4*>(src + 4);
      bf16x8 bv;
      bv[0] = (short)f2bf(v0.x); bv[1] = (short)f2bf(v0.y);
      bv[2] = (short)f2bf(v0.z); bv[3] = (short)f2bf(v0.w);
      bv[4] = (short)f2bf(v1.x); bv[5] = (short)f2bf(v1.y);
      bv[6] = (short)f2bf(v1.z); bv[7] = (short)f2bf(v1.w);
      bF[ni] = bv;
    }
#pragma unroll
    for (int mi = 0; mi < 4; mi++)
#pragma unroll
      for (int ni = 0; ni < 4; ni++)
        acc[mi][ni] = mfma16(aF[mi], bF[ni], acc[mi][ni]);
  }
  float* dst = part + (size_t)ksp * (256 * 4096);
#pragma unroll
  for (int mi = 0; mi < 4; mi++)
#pragma unroll
    for (int ni = 0; ni < 4; ni++)
#pragma unroll
      for (int r = 0; r < 4; r++) {
        int b = w * 64 + mi * 16 + lh * 4 + r;
        int j = n0 + ni * 16 + lr;
        dst[(size_t)b * 4096 + j] = acc[mi][ni][r];
      }
}

// ---------------- LSTM pointwise: reduce split-K partials + gates + outputs ---------------
__global__ void k_lstm(const float* __restrict__ part, const float* __restrict__ bih,
                       const float* __restrict__ bhh, const float* __restrict__ c0,
                       float* __restrict__ out) {
  int idx = blockIdx.x * 256 + threadIdx.x;      // 262144
  int h = idx & 1023;
  int b = idx >> 10;
  const float* p = part + (size_t)b * 4096;
  float gi = bih[h] + bhh[h];
  float gf = bih[1024 + h] + bhh[1024 + h];
  float gg = bih[2048 + h] + bhh[2048 + h];
  float go = bih[3072 + h] + bhh[3072 + h];
#pragma unroll
  for (int ks = 0; ks < 4; ks++) {
    const float* q = p + (size_t)ks * 1048576;
    gi += q[h]; gf += q[1024 + h]; gg += q[2048 + h]; go += q[3072 + h];
  }
  float c = fast_sig(gf) * c0[idx] + fast_sig(gi) * fast_tanh(gg);
  float hv = fast_sig(go) * fast_tanh(c);
  out[131072 + idx] = hv;                        // h1
  out[393216 + idx] = c;                         // c1
}

extern "C" void kernel_launch(void* const* d_in, const int* in_sizes, int n_in,
                              void* d_out, int out_size, void* d_ws, size_t ws_size,
                              hipStream_t stream) {
  const float* qd    = (const float*)d_in[0];
  const float* qmask = (const float*)d_in[1];
  const float* inp   = (const float*)d_in[2];
  const int*   pidx  = (const int*)d_in[3];
  const float* hist  = (const float*)d_in[4];
  const float* h0    = (const float*)d_in[5];
  const float* c0    = (const float*)d_in[6];
  const float* Wih   = (const float*)d_in[7];
  const float* Whh   = (const float*)d_in[8];
  const float* bih   = (const float*)d_in[9];
  const float* bhh   = (const float*)d_in[10];
  const float* a1w   = (const float*)d_in[11];
  const float* a1b   = (const float*)d_in[12];
  const float* a2w   = (const float*)d_in[13];
  float* outF = (float*)d_out;

  char* ws = (char*)d_ws;
  unsigned short* wqf  = (unsigned short*)(ws);                 // 512 KB
  float*          base = (float*)(ws + 524288);                  // 512 KB
  float*          araw = (float*)(ws + 1048576);                 // 512 KB
  unsigned short* xf   = (unsigned short*)(ws + 2097152);        // 1.5 MB
  float*          p1   = (float*)(ws + 3670016);                 // 4 MB
  float*          pg   = (float*)(ws + 7864320);                 // 16 MB
  unsigned short* qbf  = (unsigned short*)(ws + 33554432);       // 128 MB bf16 qd copy

  (void)hipFuncSetAttribute((const void*)k_attgemm,
                            hipFuncAttributeMaxDynamicSharedMemorySize, 65536);

  k_prep   <<<384,  256, 0, stream>>>(a1w, h0, wqf, p1);
  k_base2  <<<512,  256, 0, stream>>>(p1, a1b, base);
  k_attgemm<<<2048, 256, 65536, stream>>>(qd, wqf, base, a2w, araw, qbf);
  k_ctx    <<<256,  256, 0, stream>>>(qbf, araw, qmask, outF);
  k_xf     <<<384,  256, 0, stream>>>(inp, outF, hist, pidx, h0, xf);
  k_gates  <<<256,  256, 0, stream>>>(xf, Wih, Whh, pg);
  k_lstm   <<<1024, 256, 0, stream>>>(pg, bih, bhh, c0, outF);
}